// Round 7
// baseline (448.778 us; speedup 1.0000x reference)
//
#include <hip/hip_runtime.h>

#define NN 2048
#define EPS 0.01f
#define NBLK 512          // 2 blocks per CU, persistent streamers
#define ROWS_PB 32        // 16384 total rows / 512 blocks
#define BLK_PER_B 64      // blocks per batch (64 * 32 = 2048 rows)
#define NPASS 8           // measurement: repeat the sweep 8x in-dispatch

// Native vector type: __builtin_nontemporal_load requires a real vector type.
typedef float vfloat4 __attribute__((ext_vector_type(4)));

// MEASUREMENT ROUND: identical streaming structure to round 6, but the row
// sweep runs NPASS times inside one dispatch (pass p rotates the row order by
// 4*p so address streams differ and passes can't be CSE'd). Total count is
// exactly NPASS * true count; divided out at the store (power of two, exact).
// Purpose: make stage1 long enough to (a) appear in top-5 counters and/or
// (b) expose per-pass time via the dur_us delta.
__global__ __launch_bounds__(256) void coloring_loss_stage1(
    const float* __restrict__ W,
    const float* __restrict__ pred,
    float* __restrict__ partial)
{
    __shared__ float s_partial[4];

    const int bid = blockIdx.x;
    const int b   = bid / BLK_PER_B;                 // batch
    const int i0  = (bid % BLK_PER_B) * ROWS_PB;     // first row this block owns
    const int t   = threadIdx.x;

    const float* predb = pred + (size_t)b * NN;

    // This thread's 8 comparand pred_j values -> registers (L1/L2 hits).
    const vfloat4 pj0 = ((const vfloat4*)predb)[t];
    const vfloat4 pj1 = ((const vfloat4*)predb)[t + 256];

    // W[b, 1, i0, :] base.
    const float* wbase = W + (((size_t)b * 2 + 1) * (size_t)NN + (size_t)i0) * (size_t)NN;

    int cnt = 0;
    for (int p = 0; p < NPASS; ++p) {
        const int rot = p * 4;

        // Prologue: load first row of this pass.
        {
            const vfloat4* w4 = (const vfloat4*)(wbase + (size_t)((rot) & (ROWS_PB - 1)) * NN);
            // fallthrough into pipeline below
        }
        const int r0 = rot & (ROWS_PB - 1);
        const vfloat4* w4p = (const vfloat4*)(wbase + (size_t)r0 * NN);
        vfloat4 w0 = __builtin_nontemporal_load(&w4p[t]);
        vfloat4 w1 = __builtin_nontemporal_load(&w4p[t + 256]);

        for (int rr = 0; rr < ROWS_PB; ++rr) {
            const int r = (rr + rot) & (ROWS_PB - 1);
            vfloat4 nw0, nw1;
            if (rr + 1 < ROWS_PB) {
                const int rn = (rr + 1 + rot) & (ROWS_PB - 1);
                const vfloat4* n4 = (const vfloat4*)(wbase + (size_t)rn * NN);
                nw0 = __builtin_nontemporal_load(&n4[t]);
                nw1 = __builtin_nontemporal_load(&n4[t + 256]);
            } else {
                nw0 = w0; nw1 = w1;  // dead on last iteration
            }

            const float pi = predb[i0 + r];  // uniform -> scalar load

            cnt += (w0.x == 1.0f) && (fabsf(pi - pj0.x) < EPS);
            cnt += (w0.y == 1.0f) && (fabsf(pi - pj0.y) < EPS);
            cnt += (w0.z == 1.0f) && (fabsf(pi - pj0.z) < EPS);
            cnt += (w0.w == 1.0f) && (fabsf(pi - pj0.w) < EPS);
            cnt += (w1.x == 1.0f) && (fabsf(pi - pj1.x) < EPS);
            cnt += (w1.y == 1.0f) && (fabsf(pi - pj1.y) < EPS);
            cnt += (w1.z == 1.0f) && (fabsf(pi - pj1.z) < EPS);
            cnt += (w1.w == 1.0f) && (fabsf(pi - pj1.w) < EPS);

            w0 = nw0; w1 = nw1;
        }
    }

    // Wave (64-lane) shuffle reduction.
#pragma unroll
    for (int off = 32; off > 0; off >>= 1)
        cnt += __shfl_down(cnt, off, 64);

    const int wave = t >> 6;
    const int lane = t & 63;
    if (lane == 0) s_partial[wave] = (float)cnt;
    __syncthreads();

    if (t == 0) {
        const float total = s_partial[0] + s_partial[1] + s_partial[2] + s_partial[3];
        partial[bid] = total * (1.0f / NPASS);  // exact: total is a multiple of NPASS
    }
}

// Stage 2: one block reduces the 512 partials -> out[0].
__global__ __launch_bounds__(256) void coloring_loss_stage2(
    const float* __restrict__ partial,
    float* __restrict__ out)
{
    __shared__ float s_partial[4];
    const int t = threadIdx.x;

    float s = partial[t] + partial[t + 256];

#pragma unroll
    for (int off = 32; off > 0; off >>= 1)
        s += __shfl_down(s, off, 64);

    const int wave = t >> 6;
    const int lane = t & 63;
    if (lane == 0) s_partial[wave] = s;
    __syncthreads();

    if (t == 0)
        out[0] = s_partial[0] + s_partial[1] + s_partial[2] + s_partial[3];
}

extern "C" void kernel_launch(void* const* d_in, const int* in_sizes, int n_in,
                              void* d_out, int out_size, void* d_ws, size_t ws_size,
                              hipStream_t stream) {
    const float* W    = (const float*)d_in[0];  // (8, 2, 2048, 2048) f32
    const float* pred = (const float*)d_in[1];  // (8, 2048) f32
    float* out     = (float*)d_out;
    float* partial = (float*)d_ws;  // 512 floats of scratch

    coloring_loss_stage1<<<NBLK, 256, 0, stream>>>(W, pred, partial);
    coloring_loss_stage2<<<1, 256, 0, stream>>>(partial, out);
}

// Round 8
// 322.574 us; speedup vs baseline: 1.3912x; 1.3912x over previous
//
#include <hip/hip_runtime.h>

#define NN 2048
#define EPS 0.01f
#define NBLK 512          // 2 blocks per CU, persistent streamers
#define ROWS_PB 32        // 16384 total rows / 512 blocks
#define BLK_PER_B 64      // blocks per batch (64 * 32 = 2048 rows)

// Native vector type: __builtin_nontemporal_load requires a real vector type,
// not HIP's HIP_vector_type<float,4> class.
typedef float vfloat4 __attribute__((ext_vector_type(4)));

// ROOFLINE-VERIFIED STRUCTURE (round-7 measurement): the 8-pass replica of
// this sweep ran at 20.8 µs/pass with the HBM+L3 read path saturated at
// ~6.46 TB/s aggregate. Single pass = ~21 µs vs 21.3 µs theoretical floor for
// the mandatory 134 MB W[:,1] stream. Everything else in dur_us (~300 µs) is
// harness reset overhead (1 GiB ws re-poison + input restore).
//
// Stage 1: each block sweeps 32 contiguous rows of W[b,1] (256 KB) with a
// software-pipelined row loop: prefetch row r+1's two float4 while comparing
// row r. Nontemporal loads (stream has zero reuse). pred comparands live in
// registers; row anchors are uniform scalar loads. One plain store per block.
__global__ __launch_bounds__(256) void coloring_loss_stage1(
    const float* __restrict__ W,
    const float* __restrict__ pred,
    float* __restrict__ partial)
{
    __shared__ float s_partial[4];

    const int bid = blockIdx.x;
    const int b   = bid / BLK_PER_B;                 // batch
    const int i0  = (bid % BLK_PER_B) * ROWS_PB;     // first row this block owns
    const int t   = threadIdx.x;

    const float* predb = pred + (size_t)b * NN;

    // This thread's 8 comparand pred_j values -> registers (L1/L2 hits).
    const vfloat4 pj0 = ((const vfloat4*)predb)[t];
    const vfloat4 pj1 = ((const vfloat4*)predb)[t + 256];

    // W[b, 1, i0, :] base.
    const float* wbase = W + (((size_t)b * 2 + 1) * (size_t)NN + (size_t)i0) * (size_t)NN;

    // Prologue: load row 0.
    const vfloat4* w4 = (const vfloat4*)wbase;
    vfloat4 w0 = __builtin_nontemporal_load(&w4[t]);
    vfloat4 w1 = __builtin_nontemporal_load(&w4[t + 256]);

    int cnt = 0;
    for (int r = 0; r < ROWS_PB; ++r) {
        vfloat4 nw0, nw1;
        if (r + 1 < ROWS_PB) {
            const vfloat4* n4 = (const vfloat4*)(wbase + (size_t)(r + 1) * (size_t)NN);
            nw0 = __builtin_nontemporal_load(&n4[t]);
            nw1 = __builtin_nontemporal_load(&n4[t + 256]);
        } else {
            nw0 = w0; nw1 = w1;  // dead on last iteration
        }

        const float pi = predb[i0 + r];  // uniform -> scalar load

        cnt += (w0.x == 1.0f) && (fabsf(pi - pj0.x) < EPS);
        cnt += (w0.y == 1.0f) && (fabsf(pi - pj0.y) < EPS);
        cnt += (w0.z == 1.0f) && (fabsf(pi - pj0.z) < EPS);
        cnt += (w0.w == 1.0f) && (fabsf(pi - pj0.w) < EPS);
        cnt += (w1.x == 1.0f) && (fabsf(pi - pj1.x) < EPS);
        cnt += (w1.y == 1.0f) && (fabsf(pi - pj1.y) < EPS);
        cnt += (w1.z == 1.0f) && (fabsf(pi - pj1.z) < EPS);
        cnt += (w1.w == 1.0f) && (fabsf(pi - pj1.w) < EPS);

        w0 = nw0; w1 = nw1;
    }

    // Wave (64-lane) shuffle reduction.
#pragma unroll
    for (int off = 32; off > 0; off >>= 1)
        cnt += __shfl_down(cnt, off, 64);

    const int wave = t >> 6;
    const int lane = t & 63;
    if (lane == 0) s_partial[wave] = (float)cnt;
    __syncthreads();

    if (t == 0)
        partial[bid] = s_partial[0] + s_partial[1] + s_partial[2] + s_partial[3];
}

// Stage 2: one block reduces the 512 partials -> out[0]. Overwrites out
// unconditionally (d_out is poisoned 0xAA before every timed launch).
__global__ __launch_bounds__(256) void coloring_loss_stage2(
    const float* __restrict__ partial,
    float* __restrict__ out)
{
    __shared__ float s_partial[4];
    const int t = threadIdx.x;

    float s = partial[t] + partial[t + 256];

#pragma unroll
    for (int off = 32; off > 0; off >>= 1)
        s += __shfl_down(s, off, 64);

    const int wave = t >> 6;
    const int lane = t & 63;
    if (lane == 0) s_partial[wave] = s;
    __syncthreads();

    if (t == 0)
        out[0] = s_partial[0] + s_partial[1] + s_partial[2] + s_partial[3];
}

extern "C" void kernel_launch(void* const* d_in, const int* in_sizes, int n_in,
                              void* d_out, int out_size, void* d_ws, size_t ws_size,
                              hipStream_t stream) {
    const float* W    = (const float*)d_in[0];  // (8, 2, 2048, 2048) f32
    const float* pred = (const float*)d_in[1];  // (8, 2048) f32
    // d_in[2] (tgt) unused by the loss.
    float* out     = (float*)d_out;
    float* partial = (float*)d_ws;  // 512 floats of scratch

    coloring_loss_stage1<<<NBLK, 256, 0, stream>>>(W, pred, partial);
    coloring_loss_stage2<<<1, 256, 0, stream>>>(partial, out);
}